// Round 6
// baseline (94.456 us; speedup 1.0000x reference)
//
#include <hip/hip_runtime.h>
#include <hip/hip_bf16.h>

// Chamfer loss: pred [8,4096,3] f32, gt [8,4096,3] f32 -> scalar f32.
// loss = mean_b[ mean(d1)+mean(d2) + 3*(mean(top2048(d1)) + mean(top2048(d2))) ]
// d1[n] = sqrt(min_m ||p_n - g_m||^2), d2 symmetric.
//
// Fixed floor: harness re-poisons the 256 MB d_ws every timed iteration
// (~40.5 us fillBuffer) — untouchable, every contender pays it.
//
// Round-6: 16x16x32 MFMA kernel measured ~40 us (back-solved; just under the
// top-5 cutoff). Its DS pressure: 4096 ds_read_b64/CU, only 256 pairs/MFMA.
// Switch to mfma_f32_32x32x16_f16: 1024 pairs/MFMA, all low-32 lanes carry
// real B data per read -> 1024 ds_read_b64/CU (4x fewer), 4x fewer MFMAs.
//   sqd[q][g] = qn_fp32 + A.B, A=(qx,qy,qz,1,0..) f16, B=(-2gx,-2gy,-2gz,gn,0..)
// Layouts (gfx950): A[m=lane%32][k=(lane/32)*8+j], B[k=(lane/32)*8+j][n=lane%32],
// C/D col=lane&31, row=(reg&3)+8*(reg>>2)+4*(lane>>5)  [m74/m101-verified C/D].

#define BATCH 8
#define NPTS  4096
#define TOPK  2048
#define BT    256
#define NROW  (2 * BATCH)      // 16 rows = b*2+dir
#define NTILE (NPTS / 32)      // 128 g-tiles of 32 per wave

typedef _Float16 half8 __attribute__((ext_vector_type(8)));
typedef float floatx16 __attribute__((ext_vector_type(16)));

static __device__ inline unsigned pack_h2(float a, float b) {
  unsigned short ua = __builtin_bit_cast(unsigned short, (_Float16)a);
  unsigned short ub = __builtin_bit_cast(unsigned short, (_Float16)b);
  return (unsigned)ua | ((unsigned)ub << 16);
}

// ---------------- Kernel A: min squared distance via 32x32 MFMA ------------
// grid (32,16) = 512 blocks -> 2 blocks/CU, 8 waves/CU. Each wave: 32 queries
// x all 4096 g = 128 MFMAs, running min in 16 C-regs via v_min3 folds.
__global__ __launch_bounds__(BT) void nn_min_kernel(
    const float* __restrict__ pred, const float* __restrict__ gt,
    float* __restrict__ minsq /* [NROW][NPTS] */, float* __restrict__ out) {
  const int qb  = blockIdx.x;          // 0..31: query block of 128
  const int bz  = blockIdx.y;          // b*2 + dir
  const int b   = bz >> 1;
  const int dir = bz & 1;
  const float* q = (dir == 0 ? pred : gt) + (size_t)b * NPTS * 3;
  const float* g = (dir == 0 ? gt : pred) + (size_t)b * NPTS * 3;

  // db staged as f16x4 (-2x,-2y,-2z,|g|^2) in uint2; gsh[NPTS] = zero slot
  // (broadcast target for lanes 32..63, whose B k-rows 8..15 are all zero).
  __shared__ uint2 gsh[NPTS + 8];
  const int tid = threadIdx.x;

#pragma unroll
  for (int s = 0; s < NPTS / BT; s++) {
    int gi = tid + BT * s;
    float x = g[3 * gi + 0];
    float y = g[3 * gi + 1];
    float z = g[3 * gi + 2];
    float gn = x * x + y * y + z * z;
    gsh[gi] = make_uint2(pack_h2(-2.0f * x, -2.0f * y), pack_h2(-2.0f * z, gn));
  }
  if (tid == 0) gsh[NPTS] = make_uint2(0u, 0u);
  if (tid == 0 && qb == 0 && bz == 0) out[0] = 0.0f;  // select accumulates here

  const int lane = tid & 63;
  const int wave = tid >> 6;
  const int col  = lane & 31;
  const int half = lane >> 5;
  const int q0w  = qb * 128 + wave * 32;   // this wave's 32 queries

  // Every lane computes exact fp32 qn for query m=col (halves duplicate, so
  // the epilogue shuffle source is valid wave-wide).
  float qx = q[3 * (q0w + col) + 0];
  float qy = q[3 * (q0w + col) + 1];
  float qz = q[3 * (q0w + col) + 2];
  float qn = qx * qx + qy * qy + qz * qz;

  // A fragment: lanes<32 hold A[m=col][k=0..7] = (qx,qy,qz,1,0,0,0,0);
  // lanes>=32 hold k=8..15 rows: all zero.
  half8 afrag = {};
  if (half == 0) {
    afrag[0] = (_Float16)qx;
    afrag[1] = (_Float16)qy;
    afrag[2] = (_Float16)qz;
    afrag[3] = (_Float16)1.0f;
  }
  __syncthreads();

  // B address: lanes<32 read gsh[t*32+col] (2 lanes/bank -> conflict-free);
  // lanes>=32 broadcast-read the zero slot.
  const char* lds = (const char*)gsh;
  int off  = (half == 0) ? col * 8 : NPTS * 8;
  int step = (half == 0) ? 32 * 8 : 0;

  floatx16 macc;
#pragma unroll
  for (int r = 0; r < 16; r++) macc[r] = 3.0e38f;
  const floatx16 czero = {};

#pragma unroll 2
  for (int t = 0; t < NTILE; t += 2) {
    uint2 w0 = *(const uint2*)(lds + off);
    uint2 w1 = *(const uint2*)(lds + off + step);
    off += 2 * step;
    union { int4 i; half8 h; } b0, b1;
    b0.i = make_int4((int)w0.x, (int)w0.y, 0, 0);
    b1.i = make_int4((int)w1.x, (int)w1.y, 0, 0);
    floatx16 r0 = __builtin_amdgcn_mfma_f32_32x32x16_f16(afrag, b0.h, czero, 0, 0, 0);
    floatx16 r1 = __builtin_amdgcn_mfma_f32_32x32x16_f16(afrag, b1.h, czero, 0, 0, 0);
#pragma unroll
    for (int r = 0; r < 16; r++)
      macc[r] = fminf(macc[r], fminf(r0[r], r1[r]));   // v_min3 fold
  }

  // Min across the 32 g-columns (xor masks stay within each 32-lane half).
#pragma unroll
  for (int mask = 1; mask < 32; mask <<= 1) {
#pragma unroll
    for (int r = 0; r < 16; r++)
      macc[r] = fminf(macc[r], __shfl_xor(macc[r], mask));
  }

  // Rows: row = (reg&3) + 8*(reg>>2) + 4*half. Add exact fp32 qn (shuffled
  // from the owning lane), clamp, store one float4 per reg-group.
  float* dst = minsq + (size_t)bz * NPTS + q0w;
#pragma unroll
  for (int rg = 0; rg < 4; rg++) {
    const int row0 = 8 * rg + 4 * half;
    float4 outv;
#pragma unroll
    for (int e = 0; e < 4; e++) {
      float qn_s = __shfl(qn, row0 + e);   // wave-wide; qn valid in all lanes
      ((float*)&outv)[e] = fmaxf(qn_s + macc[rg * 4 + e], 0.0f);
    }
    if (col == 0) *(float4*)(dst + row0) = outv;
  }
}

// ---------------- Kernel B: sqrt + mean + exact top-k mean per row,
// then atomicAdd into out (out zeroed by nn_min, prior dispatch) ------------
__global__ __launch_bounds__(BT) void select_kernel(
    const float* __restrict__ minsq, float* __restrict__ out) {
  const int row = blockIdx.x;                // 0..15 = b*2+dir
  const float* src = minsq + (size_t)row * NPTS;
  const int tid = threadIdx.x;

  __shared__ float sf[4];
  __shared__ int   si[4];

  const int PER = NPTS / BT;  // 16 values per thread
  float d[PER];
  float sum_all = 0.0f;
#pragma unroll
  for (int j = 0; j < PER; j++) {
    float v = sqrtf(src[tid + BT * j]);
    d[j] = v;
    sum_all += v;
  }

  // block float sum of sum_all
  {
    float v = sum_all;
    for (int off = 32; off > 0; off >>= 1) v += __shfl_down(v, off);
    if ((tid & 63) == 0) sf[tid >> 6] = v;
    __syncthreads();
    sum_all = sf[0] + sf[1] + sf[2] + sf[3];
    __syncthreads();
  }

  // radix-select the TOPK-th largest value (exact, over float bit patterns)
  unsigned sel = 0u;
  for (int bit = 30; bit >= 0; --bit) {   // sign bit is 0 (nonneg)
    unsigned cand = sel | (1u << bit);
    int c = 0;
#pragma unroll
    for (int j = 0; j < PER; j++) c += (__float_as_uint(d[j]) >= cand) ? 1 : 0;
    for (int off = 32; off > 0; off >>= 1) c += __shfl_down(c, off);
    if ((tid & 63) == 0) si[tid >> 6] = c;
    __syncthreads();
    int total = si[0] + si[1] + si[2] + si[3];
    __syncthreads();
    if (total >= TOPK) sel = cand;
  }

  // sum of strictly-greater values + count
  int cgt = 0;
  float sgt = 0.0f;
#pragma unroll
  for (int j = 0; j < PER; j++) {
    if (__float_as_uint(d[j]) > sel) { cgt++; sgt += d[j]; }
  }
  {
    float v = sgt;
    for (int off = 32; off > 0; off >>= 1) v += __shfl_down(v, off);
    if ((tid & 63) == 0) sf[tid >> 6] = v;
    int c = cgt;
    for (int off = 32; off > 0; off >>= 1) c += __shfl_down(c, off);
    if ((tid & 63) == 0) si[tid >> 6] = c;
    __syncthreads();
    sgt = sf[0] + sf[1] + sf[2] + sf[3];
    cgt = si[0] + si[1] + si[2] + si[3];
  }

  if (tid == 0) {
    float kth = __uint_as_float(sel);
    float topk_sum = sgt + (float)(TOPK - cgt) * kth;  // tie-exact vs lax.top_k
    float rowval = sum_all / (float)NPTS + 3.0f * (topk_sum / (float)TOPK);
    atomicAdd(out, rowval * (1.0f / (float)BATCH));
  }
}

extern "C" void kernel_launch(void* const* d_in, const int* in_sizes, int n_in,
                              void* d_out, int out_size, void* d_ws, size_t ws_size,
                              hipStream_t stream) {
  const float* pred = (const float*)d_in[0];
  const float* gt   = (const float*)d_in[1];
  float* out = (float*)d_out;

  float* minsq = (float*)d_ws;   // [NROW][NPTS] = 256 KB

  dim3 gridA(NPTS / 128, NROW);  // (32,16) = 512 blocks
  nn_min_kernel<<<gridA, BT, 0, stream>>>(pred, gt, minsq, out);
  select_kernel<<<NROW, BT, 0, stream>>>(minsq, out);
}